// Round 5
// baseline (185.555 us; speedup 1.0000x reference)
//
#include <hip/hip_runtime.h>

// B=2,H=8,L=1024,D=64 -> 16 independent heads. Fully fused chunked causal
// linear attention: 1 kernel, 1 block per head, KV state resident in LDS.
#define NH   16
#define LSEQ 1024
#define DH   64
#define TC   64
#define NC   16

#define SCALE 1.53398078788564122971e-3f // (pi/2)/1024

typedef __attribute__((ext_vector_type(8))) short bf16x8;
typedef __attribute__((ext_vector_type(4))) float f32x4;

__device__ __forceinline__ short f2b(float x) {
    union { float f; unsigned u; } v; v.f = x;
    return (short)((v.u + 0x7FFFu + ((v.u >> 16) & 1u)) >> 16);
}
__device__ __forceinline__ float relu(float x) { return fmaxf(x, 0.f); }

__global__ __launch_bounds__(1024, 4) void fused_attn(
    const float* __restrict__ q, const float* __restrict__ k,
    const float* __restrict__ v, float* __restrict__ out)
{
    // LDS: ~122 KB -> 1 block/CU; 16 blocks total (one per head)
    __shared__ __align__(16) short Ks[TC][136];    // k_[l][d2] row-major
    __shared__ __align__(16) short KT[128][72];    // k_^T[d2][l]
    __shared__ __align__(16) short VT[80][72];     // v^T[m][l]; row 64 = ones; 65..79 = 0
    __shared__ __align__(16) short Ps[TC][72];     // masked P[l][j]
    __shared__ __align__(16) float KVf[80][136];   // fp32 KV state [m_ext][d2]
    __shared__ __align__(16) short KVT[80][136];   // bf16 mirror for MFMA B-frags

    const int n = blockIdx.x;
    const int t = threadIdx.x;
    const int lane = t & 63;
    const int w = t >> 6, wm = w >> 2, wn = w & 3;   // 4x4 wave grid
    const int quad = lane >> 4, r16 = lane & 15;

    // ---- init: zero KV state; VT = 0 except row 64 cols 0..63 = bf16 1.0.
    // SINGLE WRITER PER ELEMENT (R4 bug: separate ones-write raced the zero fill).
    for (int e = t; e < 80 * 136; e += 1024) { (&KVf[0][0])[e] = 0.f; (&KVT[0][0])[e] = 0; }
    for (int e = t; e < 80 * 72; e += 1024) {
        int row = e / 72, col = e - row * 72;
        (&VT[0][0])[e] = (row == 64 && col < 64) ? (short)0x3F80 : (short)0;
    }

    // staging coords: thread -> one float4 of the 64x64 chunk
    const int pl = t >> 4, pd = (t & 15) << 2;
    const float* kb = k + (size_t)n * LSEQ * DH;
    const float* vb = v + (size_t)n * LSEQ * DH;
    const float* qg = q + (size_t)n * LSEQ * DH;
    const int lq = 16 * wm + r16;   // this lane's Q row within the chunk

    // ---- prefetch chunk 0 ----
    float4 kf4, vf4, qa0, qa1, qc0, qc1;
    {
        kf4 = *(const float4*)(kb + pl * DH + pd);
        vf4 = *(const float4*)(vb + pl * DH + pd);
        const float* qr = qg + (size_t)lq * DH;
        qa0 = *(const float4*)(qr + quad * 8);
        qa1 = *(const float4*)(qr + quad * 8 + 4);
        qc0 = *(const float4*)(qr + 32 + quad * 8);
        qc1 = *(const float4*)(qr + 32 + quad * 8 + 4);
    }

    for (int c = 0; c < NC; ++c) {
        __syncthreads();   // (a) prev phase-3 LDS reads done; init visible at c=0

        // ---- stage K/V from prefetched regs ----
        {
            float th = SCALE * (float)(c * TC + pl + 1);
            float sl = __sinf(th), cl = __cosf(th);
            float k0 = relu(kf4.x), k1 = relu(kf4.y), k2 = relu(kf4.z), k3 = relu(kf4.w);
            short s0 = f2b(k0 * sl), s1 = f2b(k1 * sl), s2 = f2b(k2 * sl), s3 = f2b(k3 * sl);
            short c0 = f2b(k0 * cl), c1 = f2b(k1 * cl), c2 = f2b(k2 * cl), c3 = f2b(k3 * cl);
            *(short4*)&Ks[pl][pd]      = make_short4(s0, s1, s2, s3);
            *(short4*)&Ks[pl][pd + 64] = make_short4(c0, c1, c2, c3);
            KT[pd + 0][pl] = s0; KT[pd + 1][pl] = s1; KT[pd + 2][pl] = s2; KT[pd + 3][pl] = s3;
            KT[pd + 64][pl] = c0; KT[pd + 65][pl] = c1; KT[pd + 66][pl] = c2; KT[pd + 67][pl] = c3;
            VT[pd + 0][pl] = f2b(relu(vf4.x)); VT[pd + 1][pl] = f2b(relu(vf4.y));
            VT[pd + 2][pl] = f2b(relu(vf4.z)); VT[pd + 3][pl] = f2b(relu(vf4.w));
        }

        // ---- build Q A-frags (regs, no LDS) ----
        bf16x8 qf[4];
        {
            float th = SCALE * (float)(c * TC + lq + 1);
            float sq = __sinf(th), cq = __cosf(th);
            float a[8] = { relu(qa0.x), relu(qa0.y), relu(qa0.z), relu(qa0.w),
                           relu(qa1.x), relu(qa1.y), relu(qa1.z), relu(qa1.w) };
            float b[8] = { relu(qc0.x), relu(qc0.y), relu(qc0.z), relu(qc0.w),
                           relu(qc1.x), relu(qc1.y), relu(qc1.z), relu(qc1.w) };
#pragma unroll
            for (int j = 0; j < 8; ++j) {
                qf[0][j] = f2b(a[j] * sq);
                qf[1][j] = f2b(b[j] * sq);
                qf[2][j] = f2b(a[j] * cq);
                qf[3][j] = f2b(b[j] * cq);
            }
        }
        __syncthreads();   // (b) staging visible

        // ---- prefetch chunk c+1 (latency overlaps phase 2/3 compute) ----
        if (c + 1 < NC) {
            int off = (c + 1) * TC;
            kf4 = *(const float4*)(kb + (size_t)(off + pl) * DH + pd);
            vf4 = *(const float4*)(vb + (size_t)(off + pl) * DH + pd);
            const float* qr = qg + (size_t)(off + lq) * DH;
            qa0 = *(const float4*)(qr + quad * 8);
            qa1 = *(const float4*)(qr + quad * 8 + 4);
            qc0 = *(const float4*)(qr + 32 + quad * 8);
            qc1 = *(const float4*)(qr + 32 + quad * 8 + 4);
        }

        // ---- phase 2: S tile, O_inter (reads OLD KVT), chunk KV sums ----
        f32x4 accS = f32x4{0.f, 0.f, 0.f, 0.f};
#pragma unroll
        for (int ki = 0; ki < 4; ++ki) {
            bf16x8 kf = *(const bf16x8*)&Ks[16 * wn + r16][ki * 32 + quad * 8];
            accS = __builtin_amdgcn_mfma_f32_16x16x32_bf16(qf[ki], kf, accS, 0, 0, 0);
        }
        f32x4 accOn = f32x4{0.f, 0.f, 0.f, 0.f};
        f32x4 accOd = f32x4{0.f, 0.f, 0.f, 0.f};
#pragma unroll
        for (int ki = 0; ki < 4; ++ki) {
            bf16x8 b1 = *(const bf16x8*)&KVT[16 * wn + r16][ki * 32 + quad * 8];
            accOn = __builtin_amdgcn_mfma_f32_16x16x32_bf16(qf[ki], b1, accOn, 0, 0, 0);
            bf16x8 b2 = *(const bf16x8*)&KVT[64 + r16][ki * 32 + quad * 8];
            accOd = __builtin_amdgcn_mfma_f32_16x16x32_bf16(qf[ki], b2, accOd, 0, 0, 0);
        }
        f32x4 kv0 = f32x4{0.f, 0.f, 0.f, 0.f}, kv1 = f32x4{0.f, 0.f, 0.f, 0.f};
        f32x4 kv2 = f32x4{0.f, 0.f, 0.f, 0.f}, kv3 = f32x4{0.f, 0.f, 0.f, 0.f};
#pragma unroll
        for (int ki = 0; ki < 2; ++ki) {
            bf16x8 af  = *(const bf16x8*)&VT[16 * wm + r16][ki * 32 + quad * 8];
            bf16x8 bf0 = *(const bf16x8*)&KT[16 * wn + r16][ki * 32 + quad * 8];
            bf16x8 bf1 = *(const bf16x8*)&KT[16 * (wn + 4) + r16][ki * 32 + quad * 8];
            kv0 = __builtin_amdgcn_mfma_f32_16x16x32_bf16(af, bf0, kv0, 0, 0, 0);
            kv1 = __builtin_amdgcn_mfma_f32_16x16x32_bf16(af, bf1, kv1, 0, 0, 0);
            if (wm == 0) {
                bf16x8 ad = *(const bf16x8*)&VT[64 + r16][ki * 32 + quad * 8];
                kv2 = __builtin_amdgcn_mfma_f32_16x16x32_bf16(ad, bf0, kv2, 0, 0, 0);
                kv3 = __builtin_amdgcn_mfma_f32_16x16x32_bf16(ad, bf1, kv3, 0, 0, 0);
            }
        }
        // masked P -> LDS (C-layout -> A-layout round trip)
#pragma unroll
        for (int reg = 0; reg < 4; ++reg) {
            int row = 16 * wm + quad * 4 + reg;
            int col = 16 * wn + r16;
            Ps[row][col] = f2b(col <= row ? accS[reg] : 0.f);
        }
        __syncthreads();   // (c)

        // ---- phase 3: KV state += chunk sums; O_intra; epilogue ----
#pragma unroll
        for (int reg = 0; reg < 4; ++reg) {
            int row = 16 * wm + quad * 4 + reg;
            int ca = 16 * wn + r16, cb = 16 * (wn + 4) + r16;
            float n0 = KVf[row][ca] + kv0[reg]; KVf[row][ca] = n0; KVT[row][ca] = f2b(n0);
            float n1 = KVf[row][cb] + kv1[reg]; KVf[row][cb] = n1; KVT[row][cb] = f2b(n1);
            if (wm == 0) {
                int rowd = 64 + quad * 4 + reg;
                float n2 = KVf[rowd][ca] + kv2[reg]; KVf[rowd][ca] = n2; KVT[rowd][ca] = f2b(n2);
                float n3 = KVf[rowd][cb] + kv3[reg]; KVf[rowd][cb] = n3; KVT[rowd][cb] = f2b(n3);
            }
        }
#pragma unroll
        for (int ki = 0; ki < 2; ++ki) {
            bf16x8 pf  = *(const bf16x8*)&Ps[16 * wm + r16][ki * 32 + quad * 8];
            bf16x8 vf0 = *(const bf16x8*)&VT[16 * wn + r16][ki * 32 + quad * 8];
            bf16x8 vfd = *(const bf16x8*)&VT[64 + r16][ki * 32 + quad * 8];
            accOn = __builtin_amdgcn_mfma_f32_16x16x32_bf16(pf, vf0, accOn, 0, 0, 0);
            accOd = __builtin_amdgcn_mfma_f32_16x16x32_bf16(pf, vfd, accOd, 0, 0, 0);
        }
        // denom lives in col 64 (lanes r16==0); broadcast within quad group
#pragma unroll
        for (int reg = 0; reg < 4; ++reg) {
            float den = __shfl(accOd[reg], lane & 48, 64);
            float inv = 1.0f / fmaxf(den, 1e-6f);
            int l = c * TC + 16 * wm + quad * 4 + reg;
            out[(size_t)(n * LSEQ + l) * DH + 16 * wn + r16] = accOn[reg] * inv;
        }
    }
}

// ---------------------------------------------------------------------------
extern "C" void kernel_launch(void* const* d_in, const int* in_sizes, int n_in,
                              void* d_out, int out_size, void* d_ws, size_t ws_size,
                              hipStream_t stream) {
    (void)in_sizes; (void)n_in; (void)out_size; (void)d_ws; (void)ws_size;
    const float* q = (const float*)d_in[0];
    const float* k = (const float*)d_in[1];
    const float* v = (const float*)d_in[2];
    float* out = (float*)d_out;

    fused_attn<<<dim3(NH), 1024, 0, stream>>>(q, k, v, out);
}

// Round 6
// 143.778 us; speedup vs baseline: 1.2906x; 1.2906x over previous
//
#include <hip/hip_runtime.h>
#include <stdint.h>

// B=2,H=8,L=1024,D=64 -> 16 heads x 16 chunks of 64. Each (head,chunk) block
// recomputes its KV prefix from bf16 slabs prepped by kernel 1 (no serial chain).
#define NH   16
#define LSEQ 1024
#define DH   64
#define D2   128
#define TC   64
#define NC   16
#define SCALE 1.53398078788564122971e-3f // (pi/2)/1024

typedef __attribute__((ext_vector_type(8))) short bf16x8;
typedef __attribute__((ext_vector_type(4))) float f32x4;

__device__ __forceinline__ short f2b(float x) {
    union { float f; unsigned u; } v; v.f = x;
    return (short)((v.u + 0x7FFFu + ((v.u >> 16) & 1u)) >> 16);
}

// ws layout (bytes). Slabs indexed by slab = n*NC + j.
// KjT: [128][72] shorts = 18432 B  (K~^T[d2][l], 8-short row pad -> 2-way-free banks)
// VjT: [64][72]  shorts = 9216 B   (V~^T[m][l])
// Ksr: [64][136] shorts = 17408 B  (K~ row-major [l][d2], pad 8)
// ksum: 128 floats = 512 B         (per-chunk sum_l k~[l][d2])
#define KJT_B 0
#define VJT_B 4718592
#define KSR_B (4718592 + 2359296)
#define KSUM_B (4718592 + 2359296 + 4456448)
#define KJT_U4 1152
#define VJT_U4 576
#define KSR_U4 1088

// ---------------------------------------------------------------------------
__global__ __launch_bounds__(256, 2) void prep(
    const float* __restrict__ k, const float* __restrict__ v,
    void* __restrict__ ws)
{
    __shared__ __align__(16) float Kst[64][68];
    __shared__ __align__(16) float Vst[64][68];
    __shared__ float sA[64], cA[64];

    const int bx = blockIdx.x, n = bx & 15, j = bx >> 4, slab = n * NC + j;
    const int t = threadIdx.x;
    {
        const int l = t >> 2, db = (t & 3) << 4;
        const float* kp = k + (size_t)(n * LSEQ + j * TC + l) * DH + db;
        const float* vp = v + (size_t)(n * LSEQ + j * TC + l) * DH + db;
#pragma unroll
        for (int i = 0; i < 4; ++i) {
            float4 a = *(const float4*)(kp + 4 * i);
            Kst[l][db + 4*i + 0] = fmaxf(a.x, 0.f); Kst[l][db + 4*i + 1] = fmaxf(a.y, 0.f);
            Kst[l][db + 4*i + 2] = fmaxf(a.z, 0.f); Kst[l][db + 4*i + 3] = fmaxf(a.w, 0.f);
            float4 b = *(const float4*)(vp + 4 * i);
            Vst[l][db + 4*i + 0] = fmaxf(b.x, 0.f); Vst[l][db + 4*i + 1] = fmaxf(b.y, 0.f);
            Vst[l][db + 4*i + 2] = fmaxf(b.z, 0.f); Vst[l][db + 4*i + 3] = fmaxf(b.w, 0.f);
        }
    }
    if (t < 64) {
        float th = SCALE * (float)(j * TC + t + 1);
        sA[t] = __sinf(th); cA[t] = __cosf(th);
    }
    __syncthreads();

    short* kjt = (short*)((char*)ws + KJT_B) + (size_t)slab * 9216;
    short* vjt = (short*)((char*)ws + VJT_B) + (size_t)slab * 4608;
    short* ksr = (short*)((char*)ws + KSR_B) + (size_t)slab * 8704;
    float* ksm = (float*)((char*)ws + KSUM_B) + (size_t)slab * 128;

    alignas(16) short pk[8];
    alignas(16) short zz[8] = {0,0,0,0,0,0,0,0};
    if (t < 128) {
        const int d2 = t, d = t & 63; const bool sp = t < 64;
        float sum = 0.f;
        short* row = kjt + d2 * 72;
#pragma unroll
        for (int i8 = 0; i8 < 8; ++i8) {
#pragma unroll
            for (int i = 0; i < 8; ++i) {
                int l = i8 * 8 + i;
                float f = Kst[l][d] * (sp ? sA[l] : cA[l]);
                sum += f; pk[i] = f2b(f);
            }
            *(uint4*)(row + i8 * 8) = *(uint4*)pk;
        }
        *(uint4*)(row + 64) = *(uint4*)zz;
        ksm[d2] = sum;
    } else if (t < 192) {
        const int m = t - 128;
        short* row = vjt + m * 72;
#pragma unroll
        for (int i8 = 0; i8 < 8; ++i8) {
#pragma unroll
            for (int i = 0; i < 8; ++i) pk[i] = f2b(Vst[i8 * 8 + i][m]);
            *(uint4*)(row + i8 * 8) = *(uint4*)pk;
        }
        *(uint4*)(row + 64) = *(uint4*)zz;
    } else {
        const int l = t - 192;
        short* row = ksr + l * 136;
#pragma unroll
        for (int i8 = 0; i8 < 8; ++i8) {
#pragma unroll
            for (int i = 0; i < 8; ++i) pk[i] = f2b(Kst[l][i8 * 8 + i] * sA[l]);
            *(uint4*)(row + i8 * 8) = *(uint4*)pk;
        }
#pragma unroll
        for (int i8 = 0; i8 < 8; ++i8) {
#pragma unroll
            for (int i = 0; i < 8; ++i) pk[i] = f2b(Kst[l][i8 * 8 + i] * cA[l]);
            *(uint4*)(row + 64 + i8 * 8) = *(uint4*)pk;
        }
        *(uint4*)(row + 128) = *(uint4*)zz;
    }
}

// ---------------------------------------------------------------------------
__global__ __launch_bounds__(256, 2) void attn(
    const float* __restrict__ q, const void* __restrict__ ws,
    float* __restrict__ out)
{
    __shared__ __align__(16) short KjT[128][72];
    __shared__ __align__(16) short VjT[64][72];   // prefix V slab; later own-chunk V~^T
    __shared__ __align__(16) short Ks[64][136];   // own-chunk K~ row-major
    __shared__ __align__(16) short KVT[80][136];  // KV prefix [m][d2]; row64=kcum; 65..79=0
    __shared__ __align__(16) short Ps[64][72];

    const int bx = blockIdx.x, n = bx & 15, c = bx >> 4;
    const int t = threadIdx.x, lane = t & 63, w = t >> 6;
    const int quad = lane >> 4, r16 = lane & 15;

    const uint4* kjt_u = (const uint4*)((const char*)ws + KJT_B);
    const uint4* vjt_u = (const uint4*)((const char*)ws + VJT_B);
    const uint4* ksr_u = (const uint4*)((const char*)ws + KSR_B);
    const float* ksm   = (const float*)((const char*)ws + KSUM_B);

    // zero KVT rows 65..79 (read by denom B-frags, never written otherwise)
    if (t < 255) ((uint4*)&KVT[65][0])[t] = uint4{0, 0, 0, 0};
    // kcum (fp32 sum of per-chunk ksum) -> KVT row 64
    if (t < 128) {
        float kc = 0.f;
        for (int j = 0; j < c; ++j) kc += ksm[(size_t)(n * NC + j) * 128 + t];
        KVT[64][t] = f2b(kc);
    }

    // ---- prefix: KV[m][d2] = sum over prior chunks of V~^T x K~ ----
    f32x4 acc[4][2];
#pragma unroll
    for (int mt = 0; mt < 4; ++mt) { acc[mt][0] = f32x4{0,0,0,0}; acc[mt][1] = f32x4{0,0,0,0}; }

    uint4 rk[5], rv[3];
    auto preload = [&](int j) {
        const uint4* sk = kjt_u + (size_t)(n * NC + j) * KJT_U4;
#pragma unroll
        for (int i = 0; i < 5; ++i) { int idx = t + 256 * i; if (idx < KJT_U4) rk[i] = sk[idx]; }
        const uint4* sv = vjt_u + (size_t)(n * NC + j) * VJT_U4;
#pragma unroll
        for (int i = 0; i < 3; ++i) { int idx = t + 256 * i; if (idx < VJT_U4) rv[i] = sv[idx]; }
    };
    if (c > 0) preload(0);

    for (int j = 0; j < c; ++j) {
        __syncthreads();   // prior iteration's frag reads done
#pragma unroll
        for (int i = 0; i < 5; ++i) { int idx = t + 256 * i; if (idx < KJT_U4) ((uint4*)&KjT[0][0])[idx] = rk[i]; }
#pragma unroll
        for (int i = 0; i < 3; ++i) { int idx = t + 256 * i; if (idx < VJT_U4) ((uint4*)&VjT[0][0])[idx] = rv[i]; }
        __syncthreads();   // slab visible
        if (j + 1 < c) preload(j + 1);   // global latency hides under MFMA

        bf16x8 bfr[2][2];
#pragma unroll
        for (int ni = 0; ni < 2; ++ni)
#pragma unroll
            for (int ks = 0; ks < 2; ++ks)
                bfr[ni][ks] = *(const bf16x8*)&KjT[16 * (2 * w + ni) + r16][ks * 32 + quad * 8];
#pragma unroll
        for (int mt = 0; mt < 4; ++mt)
#pragma unroll
            for (int ks = 0; ks < 2; ++ks) {
                bf16x8 af = *(const bf16x8*)&VjT[16 * mt + r16][ks * 32 + quad * 8];
                acc[mt][0] = __builtin_amdgcn_mfma_f32_16x16x32_bf16(af, bfr[0][ks], acc[mt][0], 0, 0, 0);
                acc[mt][1] = __builtin_amdgcn_mfma_f32_16x16x32_bf16(af, bfr[1][ks], acc[mt][1], 0, 0, 0);
            }
    }
    __syncthreads();   // all prefix reads done; safe to overwrite VjT + write KVT

    // acc -> KVT rows 0..63 (wave w owns d2 cols 32w..32w+31)
#pragma unroll
    for (int mt = 0; mt < 4; ++mt)
#pragma unroll
        for (int ni = 0; ni < 2; ++ni)
#pragma unroll
            for (int reg = 0; reg < 4; ++reg)
                KVT[16 * mt + quad * 4 + reg][32 * w + 16 * ni + r16] = f2b(acc[mt][ni][reg]);

    // own-chunk slabs: K~ row-major + V~^T
    {
        const uint4* sk = ksr_u + (size_t)(n * NC + c) * KSR_U4;
#pragma unroll
        for (int i = 0; i < 5; ++i) { int idx = t + 256 * i; if (idx < KSR_U4) ((uint4*)&Ks[0][0])[idx] = sk[idx]; }
        const uint4* sv = vjt_u + (size_t)(n * NC + c) * VJT_U4;
#pragma unroll
        for (int i = 0; i < 3; ++i) { int idx = t + 256 * i; if (idx < VJT_U4) ((uint4*)&VjT[0][0])[idx] = sv[idx]; }
    }

    // Q A-frags from global (wave w = l-tile w; lane row lq)
    bf16x8 qf[4];
    {
        const int lq = 16 * w + r16;
        const float* qr = q + (size_t)(n * LSEQ + c * TC + lq) * DH;
        float th = SCALE * (float)(c * TC + lq + 1);
        float sq = __sinf(th), cq = __cosf(th);
        float4 a0 = *(const float4*)(qr + quad * 8);
        float4 a1 = *(const float4*)(qr + quad * 8 + 4);
        float4 b0 = *(const float4*)(qr + 32 + quad * 8);
        float4 b1 = *(const float4*)(qr + 32 + quad * 8 + 4);
        float a[8] = { fmaxf(a0.x,0.f), fmaxf(a0.y,0.f), fmaxf(a0.z,0.f), fmaxf(a0.w,0.f),
                       fmaxf(a1.x,0.f), fmaxf(a1.y,0.f), fmaxf(a1.z,0.f), fmaxf(a1.w,0.f) };
        float b[8] = { fmaxf(b0.x,0.f), fmaxf(b0.y,0.f), fmaxf(b0.z,0.f), fmaxf(b0.w,0.f),
                       fmaxf(b1.x,0.f), fmaxf(b1.y,0.f), fmaxf(b1.z,0.f), fmaxf(b1.w,0.f) };
#pragma unroll
        for (int jj = 0; jj < 8; ++jj) {
            qf[0][jj] = f2b(a[jj] * sq);
            qf[1][jj] = f2b(b[jj] * sq);
            qf[2][jj] = f2b(a[jj] * cq);
            qf[3][jj] = f2b(b[jj] * cq);
        }
    }
    __syncthreads();   // Ks/VjT/KVT all visible

    // S = Q~ K~^T over own chunk
    f32x4 accS[4];
#pragma unroll
    for (int nt = 0; nt < 4; ++nt) accS[nt] = f32x4{0, 0, 0, 0};
#pragma unroll
    for (int nt = 0; nt < 4; ++nt)
#pragma unroll
        for (int ks = 0; ks < 4; ++ks) {
            bf16x8 kf = *(const bf16x8*)&Ks[16 * nt + r16][ks * 32 + quad * 8];
            accS[nt] = __builtin_amdgcn_mfma_f32_16x16x32_bf16(qf[ks], kf, accS[nt], 0, 0, 0);
        }
#pragma unroll
    for (int nt = 0; nt < 4; ++nt)
#pragma unroll
        for (int reg = 0; reg < 4; ++reg) {
            int row = 16 * w + quad * 4 + reg, col = 16 * nt + r16;
            Ps[row][col] = f2b(col <= row ? accS[nt][reg] : 0.f);
        }
    __syncthreads();

    // O = P V~ + Q~ KV ; denom = P·ones + Q~·kcum
    bf16x8 pf[2];
    pf[0] = *(const bf16x8*)&Ps[16 * w + r16][quad * 8];
    pf[1] = *(const bf16x8*)&Ps[16 * w + r16][32 + quad * 8];
    bf16x8 ones;
#pragma unroll
    for (int jj = 0; jj < 8; ++jj) ones[jj] = (short)0x3F80;

    f32x4 accO[4], accD = f32x4{0, 0, 0, 0};
#pragma unroll
    for (int nt = 0; nt < 4; ++nt) accO[nt] = f32x4{0, 0, 0, 0};
#pragma unroll
    for (int nt = 0; nt < 4; ++nt) {
#pragma unroll
        for (int ks = 0; ks < 4; ++ks) {
            bf16x8 bfv = *(const bf16x8*)&KVT[16 * nt + r16][ks * 32 + quad * 8];
            accO[nt] = __builtin_amdgcn_mfma_f32_16x16x32_bf16(qf[ks], bfv, accO[nt], 0, 0, 0);
        }
#pragma unroll
        for (int ks = 0; ks < 2; ++ks) {
            bf16x8 vv = *(const bf16x8*)&VjT[16 * nt + r16][ks * 32 + quad * 8];
            accO[nt] = __builtin_amdgcn_mfma_f32_16x16x32_bf16(pf[ks], vv, accO[nt], 0, 0, 0);
        }
    }
#pragma unroll
    for (int ks = 0; ks < 4; ++ks) {
        bf16x8 bfd = *(const bf16x8*)&KVT[64 + r16][ks * 32 + quad * 8];
        accD = __builtin_amdgcn_mfma_f32_16x16x32_bf16(qf[ks], bfd, accD, 0, 0, 0);
    }
    accD = __builtin_amdgcn_mfma_f32_16x16x32_bf16(pf[0], ones, accD, 0, 0, 0);
    accD = __builtin_amdgcn_mfma_f32_16x16x32_bf16(pf[1], ones, accD, 0, 0, 0);

#pragma unroll
    for (int reg = 0; reg < 4; ++reg) {
        float den = __shfl(accD[reg], lane & 48, 64);
        float inv = 1.0f / fmaxf(den, 1e-6f);
        int l = c * TC + 16 * w + quad * 4 + reg;
        float* orow = out + (size_t)(n * LSEQ + l) * DH;
#pragma unroll
        for (int nt = 0; nt < 4; ++nt)
            orow[16 * nt + r16] = accO[nt][reg] * inv;
    }
}

// ---------------------------------------------------------------------------
extern "C" void kernel_launch(void* const* d_in, const int* in_sizes, int n_in,
                              void* d_out, int out_size, void* d_ws, size_t ws_size,
                              hipStream_t stream) {
    (void)in_sizes; (void)n_in; (void)out_size; (void)ws_size;
    const float* q = (const float*)d_in[0];
    const float* k = (const float*)d_in[1];
    const float* v = (const float*)d_in[2];
    float* out = (float*)d_out;

    prep<<<dim3(NH * NC), 256, 0, stream>>>(k, v, d_ws);
    attn<<<dim3(NH * NC), 256, 0, stream>>>(q, d_ws, out);
}

// Round 7
// 117.014 us; speedup vs baseline: 1.5857x; 1.2287x over previous
//
#include <hip/hip_runtime.h>
#include <stdint.h>

// B=2,H=8,L=1024,D=64 -> 16 heads x 16 chunks of 64.
// prep: bf16 slabs + fp32 per-chunk KV sums (MFMA).  scan: exclusive prefix
// over chunks (16 blocks, XCD-aligned with prep writes).  attn: O(1) staging,
// no loops -> S/P/O MFMAs.
#define NH   16
#define LSEQ 1024
#define DH   64
#define D2   128
#define TC   64
#define NC   16
#define SCALE 1.53398078788564122971e-3f // (pi/2)/1024

typedef __attribute__((ext_vector_type(8))) short bf16x8;
typedef __attribute__((ext_vector_type(4))) float f32x4;

__device__ __forceinline__ short f2b(float x) {
    union { float f; unsigned u; } v; v.f = x;
    return (short)((v.u + 0x7FFFu + ((v.u >> 16) & 1u)) >> 16);
}

// ws layout (bytes); slab = n*NC + j
// KJT [128][72] shorts (K~^T[d2][l]) ; VJT [64][72] shorts (V~^T[m][l])
// KSR [64][136] shorts (K~[l][d2])   ; KVC fp32 [65][128] (chunk KV + ksum row)
// KVP fp32 [65][128] (exclusive prefix)
#define KJT_B 0
#define VJT_B 4718592
#define KSR_B 7077888
#define KVC_B 11534336
#define KVP_B 20054016

// ---------------------------------------------------------------------------
__global__ __launch_bounds__(256, 2) void prep(
    const float* __restrict__ k, const float* __restrict__ v,
    void* __restrict__ ws)
{
    __shared__ __align__(16) float Kst[64][68];
    __shared__ __align__(16) float Vst[64][68];
    __shared__ float sA[64], cA[64];
    __shared__ __align__(16) short KjT[128][72];
    __shared__ __align__(16) short VjT[64][72];

    const int bx = blockIdx.x, n = bx & 15, j = bx >> 4, slab = n * NC + j;
    const int t = threadIdx.x;
    {
        const int l = t >> 2, db = (t & 3) << 4;
        const float* kp = k + (size_t)(n * LSEQ + j * TC + l) * DH + db;
        const float* vp = v + (size_t)(n * LSEQ + j * TC + l) * DH + db;
#pragma unroll
        for (int i = 0; i < 4; ++i) {
            float4 a = *(const float4*)(kp + 4 * i);
            Kst[l][db + 4*i + 0] = fmaxf(a.x, 0.f); Kst[l][db + 4*i + 1] = fmaxf(a.y, 0.f);
            Kst[l][db + 4*i + 2] = fmaxf(a.z, 0.f); Kst[l][db + 4*i + 3] = fmaxf(a.w, 0.f);
            float4 b = *(const float4*)(vp + 4 * i);
            Vst[l][db + 4*i + 0] = fmaxf(b.x, 0.f); Vst[l][db + 4*i + 1] = fmaxf(b.y, 0.f);
            Vst[l][db + 4*i + 2] = fmaxf(b.z, 0.f); Vst[l][db + 4*i + 3] = fmaxf(b.w, 0.f);
        }
    }
    if (t < 64) {
        float th = SCALE * (float)(j * TC + t + 1);
        sA[t] = __sinf(th); cA[t] = __cosf(th);
    }
    __syncthreads();

    short* kjt = (short*)((char*)ws + KJT_B) + (size_t)slab * 9216;
    short* vjt = (short*)((char*)ws + VJT_B) + (size_t)slab * 4608;
    short* ksr = (short*)((char*)ws + KSR_B) + (size_t)slab * 8704;
    float* kvc = (float*)((char*)ws + KVC_B) + (size_t)slab * 8320;

    alignas(16) short pk[8];
    alignas(16) short zz[8] = {0,0,0,0,0,0,0,0};
    if (t < 128) {
        const int d2 = t, d = t & 63; const bool sp = t < 64;
        float sum = 0.f;
        short* row = kjt + d2 * 72;
#pragma unroll
        for (int i8 = 0; i8 < 8; ++i8) {
#pragma unroll
            for (int i = 0; i < 8; ++i) {
                int l = i8 * 8 + i;
                float f = Kst[l][d] * (sp ? sA[l] : cA[l]);
                sum += f; pk[i] = f2b(f);
            }
            *(uint4*)(row + i8 * 8) = *(uint4*)pk;
            *(uint4*)&KjT[d2][i8 * 8] = *(uint4*)pk;
        }
        *(uint4*)(row + 64) = *(uint4*)zz;
        *(uint4*)&KjT[d2][64] = *(uint4*)zz;
        kvc[64 * 128 + d2] = sum;   // ksum row
    } else if (t < 192) {
        const int m = t - 128;
        short* row = vjt + m * 72;
#pragma unroll
        for (int i8 = 0; i8 < 8; ++i8) {
#pragma unroll
            for (int i = 0; i < 8; ++i) pk[i] = f2b(Vst[i8 * 8 + i][m]);
            *(uint4*)(row + i8 * 8) = *(uint4*)pk;
            *(uint4*)&VjT[m][i8 * 8] = *(uint4*)pk;
        }
        *(uint4*)(row + 64) = *(uint4*)zz;
        *(uint4*)&VjT[m][64] = *(uint4*)zz;
    } else {
        const int l = t - 192;
        short* row = ksr + l * 136;
#pragma unroll
        for (int i8 = 0; i8 < 8; ++i8) {
#pragma unroll
            for (int i = 0; i < 8; ++i) pk[i] = f2b(Kst[l][i8 * 8 + i] * sA[l]);
            *(uint4*)(row + i8 * 8) = *(uint4*)pk;
        }
#pragma unroll
        for (int i8 = 0; i8 < 8; ++i8) {
#pragma unroll
            for (int i = 0; i < 8; ++i) pk[i] = f2b(Kst[l][i8 * 8 + i] * cA[l]);
            *(uint4*)(row + 64 + i8 * 8) = *(uint4*)pk;
        }
        *(uint4*)(row + 128) = *(uint4*)zz;
    }
    __syncthreads();

    // MFMA: KVchunk[m][d2] = sum_l V~^T[m][l] * K~^T[d2][l]
    const int lane = t & 63, w = t >> 6, quad = lane >> 4, r16 = lane & 15;
    f32x4 acc[4][2];
#pragma unroll
    for (int mt = 0; mt < 4; ++mt) { acc[mt][0] = f32x4{0,0,0,0}; acc[mt][1] = f32x4{0,0,0,0}; }
#pragma unroll
    for (int ni = 0; ni < 2; ++ni)
#pragma unroll
        for (int ks = 0; ks < 2; ++ks) {
            bf16x8 bfr = *(const bf16x8*)&KjT[16 * (2 * w + ni) + r16][ks * 32 + quad * 8];
#pragma unroll
            for (int mt = 0; mt < 4; ++mt) {
                bf16x8 af = *(const bf16x8*)&VjT[16 * mt + r16][ks * 32 + quad * 8];
                acc[mt][ni] = __builtin_amdgcn_mfma_f32_16x16x32_bf16(af, bfr, acc[mt][ni], 0, 0, 0);
            }
        }
#pragma unroll
    for (int mt = 0; mt < 4; ++mt)
#pragma unroll
        for (int ni = 0; ni < 2; ++ni)
#pragma unroll
            for (int reg = 0; reg < 4; ++reg)
                kvc[(16 * mt + quad * 4 + reg) * 128 + 16 * (2 * w + ni) + r16] = acc[mt][ni][reg];
}

// ---------------------------------------------------------------------------
// scan: per head, exclusive fp32 prefix over 16 chunk KVs (incl. ksum row).
// blockIdx.x = head -> XCD n%8, matching prep's writes (L2-local).
__global__ __launch_bounds__(1024, 2) void scan(void* __restrict__ ws)
{
    const int n = blockIdx.x, t = threadIdx.x;
    const float4* kvc = (const float4*)((const char*)ws + KVC_B);
    float4* kvp = (float4*)((char*)ws + KVP_B);

    float4 r0 = float4{0,0,0,0}, r1 = float4{0,0,0,0}, r2 = float4{0,0,0,0};
    float4 a0, a1, a2;
    const bool t3 = (t < 32);

    {
        const float4* b = kvc + (size_t)(n * NC) * 2080;
        a0 = b[t]; a1 = b[t + 1024]; if (t3) a2 = b[t + 2048];
    }
    for (int c = 0; c < NC; ++c) {
        float4 c0 = a0, c1 = a1, c2 = a2;
        if (c + 1 < NC) {
            const float4* b = kvc + (size_t)(n * NC + c + 1) * 2080;
            a0 = b[t]; a1 = b[t + 1024]; if (t3) a2 = b[t + 2048];
        }
        float4* o = kvp + (size_t)(n * NC + c) * 2080;
        o[t] = r0; o[t + 1024] = r1; if (t3) o[t + 2048] = r2;
        r0.x += c0.x; r0.y += c0.y; r0.z += c0.z; r0.w += c0.w;
        r1.x += c1.x; r1.y += c1.y; r1.z += c1.z; r1.w += c1.w;
        if (t3) { r2.x += c2.x; r2.y += c2.y; r2.z += c2.z; r2.w += c2.w; }
    }
}

// ---------------------------------------------------------------------------
__global__ __launch_bounds__(256, 2) void attn(
    const float* __restrict__ q, const void* __restrict__ ws,
    float* __restrict__ out)
{
    __shared__ __align__(16) short Ks[64][136];
    __shared__ __align__(16) short VjT[64][72];
    __shared__ __align__(16) short KVT[80][136]; // rows0..63 KV, 64 kcum, 65..79 zero
    __shared__ __align__(16) short Ps[64][72];

    const int bx = blockIdx.x, n = bx & 15, c = bx >> 4;
    const int t = threadIdx.x, lane = t & 63, w = t >> 6;
    const int quad = lane >> 4, r16 = lane & 15;

    // ---- stage own slabs (one burst each; no loops over chunks) ----
    {
        const uint4* sk = (const uint4*)((const char*)ws + KSR_B) + (size_t)(n * NC + c) * 1088;
        uint4* dk = (uint4*)&Ks[0][0];
#pragma unroll
        for (int i = 0; i < 5; ++i) { int idx = t + 256 * i; if (idx < 1088) dk[idx] = sk[idx]; }
        const uint4* sv = (const uint4*)((const char*)ws + VJT_B) + (size_t)(n * NC + c) * 576;
        uint4* dv = (uint4*)&VjT[0][0];
#pragma unroll
        for (int i = 0; i < 3; ++i) { int idx = t + 256 * i; if (idx < 576) dv[idx] = sv[idx]; }
    }
    if (t < 255) ((uint4*)&KVT[65][0])[t] = uint4{0, 0, 0, 0};
    {
        const float4* sp = (const float4*)((const char*)ws + KVP_B) + (size_t)(n * NC + c) * 2080;
#pragma unroll
        for (int i = 0; i < 9; ++i) {
            int idx = t + 256 * i;
            if (idx < 2080) {
                float4 vv = sp[idx];
                int e = idx * 4, row = e >> 7, col = e & 127;
                *(short4*)&KVT[row][col] = make_short4(f2b(vv.x), f2b(vv.y), f2b(vv.z), f2b(vv.w));
            }
        }
    }

    // Q A-frags from global
    bf16x8 qf[4];
    {
        const int lq = 16 * w + r16;
        const float* qr = q + (size_t)(n * LSEQ + c * TC + lq) * DH;
        float th = SCALE * (float)(c * TC + lq + 1);
        float sq = __sinf(th), cq = __cosf(th);
        float4 a0 = *(const float4*)(qr + quad * 8);
        float4 a1 = *(const float4*)(qr + quad * 8 + 4);
        float4 b0 = *(const float4*)(qr + 32 + quad * 8);
        float4 b1 = *(const float4*)(qr + 32 + quad * 8 + 4);
        float a[8] = { fmaxf(a0.x,0.f), fmaxf(a0.y,0.f), fmaxf(a0.z,0.f), fmaxf(a0.w,0.f),
                       fmaxf(a1.x,0.f), fmaxf(a1.y,0.f), fmaxf(a1.z,0.f), fmaxf(a1.w,0.f) };
        float b[8] = { fmaxf(b0.x,0.f), fmaxf(b0.y,0.f), fmaxf(b0.z,0.f), fmaxf(b0.w,0.f),
                       fmaxf(b1.x,0.f), fmaxf(b1.y,0.f), fmaxf(b1.z,0.f), fmaxf(b1.w,0.f) };
#pragma unroll
        for (int jj = 0; jj < 8; ++jj) {
            qf[0][jj] = f2b(a[jj] * sq);
            qf[1][jj] = f2b(b[jj] * sq);
            qf[2][jj] = f2b(a[jj] * cq);
            qf[3][jj] = f2b(b[jj] * cq);
        }
    }
    __syncthreads();

    // S = Q~ K~^T (own chunk), mask -> P
    f32x4 accS[4];
#pragma unroll
    for (int nt = 0; nt < 4; ++nt) accS[nt] = f32x4{0, 0, 0, 0};
#pragma unroll
    for (int nt = 0; nt < 4; ++nt)
#pragma unroll
        for (int ks = 0; ks < 4; ++ks) {
            bf16x8 kf = *(const bf16x8*)&Ks[16 * nt + r16][ks * 32 + quad * 8];
            accS[nt] = __builtin_amdgcn_mfma_f32_16x16x32_bf16(qf[ks], kf, accS[nt], 0, 0, 0);
        }
#pragma unroll
    for (int nt = 0; nt < 4; ++nt)
#pragma unroll
        for (int reg = 0; reg < 4; ++reg) {
            int row = 16 * w + quad * 4 + reg, col = 16 * nt + r16;
            Ps[row][col] = f2b(col <= row ? accS[nt][reg] : 0.f);
        }
    __syncthreads();

    // O = P V~ + Q~ KV ; denom = P.ones + Q~.kcum
    bf16x8 pf[2];
    pf[0] = *(const bf16x8*)&Ps[16 * w + r16][quad * 8];
    pf[1] = *(const bf16x8*)&Ps[16 * w + r16][32 + quad * 8];
    bf16x8 ones;
#pragma unroll
    for (int jj = 0; jj < 8; ++jj) ones[jj] = (short)0x3F80;

    f32x4 accO[4], accD = f32x4{0, 0, 0, 0};
#pragma unroll
    for (int nt = 0; nt < 4; ++nt) accO[nt] = f32x4{0, 0, 0, 0};
#pragma unroll
    for (int nt = 0; nt < 4; ++nt) {
#pragma unroll
        for (int ks = 0; ks < 4; ++ks) {
            bf16x8 bfv = *(const bf16x8*)&KVT[16 * nt + r16][ks * 32 + quad * 8];
            accO[nt] = __builtin_amdgcn_mfma_f32_16x16x32_bf16(qf[ks], bfv, accO[nt], 0, 0, 0);
        }
#pragma unroll
        for (int ks = 0; ks < 2; ++ks) {
            bf16x8 vv = *(const bf16x8*)&VjT[16 * nt + r16][ks * 32 + quad * 8];
            accO[nt] = __builtin_amdgcn_mfma_f32_16x16x32_bf16(pf[ks], vv, accO[nt], 0, 0, 0);
        }
    }
#pragma unroll
    for (int ks = 0; ks < 4; ++ks) {
        bf16x8 bfd = *(const bf16x8*)&KVT[64 + r16][ks * 32 + quad * 8];
        accD = __builtin_amdgcn_mfma_f32_16x16x32_bf16(qf[ks], bfd, accD, 0, 0, 0);
    }
    accD = __builtin_amdgcn_mfma_f32_16x16x32_bf16(pf[0], ones, accD, 0, 0, 0);
    accD = __builtin_amdgcn_mfma_f32_16x16x32_bf16(pf[1], ones, accD, 0, 0, 0);

#pragma unroll
    for (int reg = 0; reg < 4; ++reg) {
        float den = __shfl(accD[reg], lane & 48, 64);
        float inv = 1.0f / fmaxf(den, 1e-6f);
        int l = c * TC + 16 * w + quad * 4 + reg;
        float* orow = out + (size_t)(n * LSEQ + l) * DH;
#pragma unroll
        for (int nt = 0; nt < 4; ++nt)
            orow[16 * nt + r16] = accO[nt][reg] * inv;
    }
}

// ---------------------------------------------------------------------------
extern "C" void kernel_launch(void* const* d_in, const int* in_sizes, int n_in,
                              void* d_out, int out_size, void* d_ws, size_t ws_size,
                              hipStream_t stream) {
    (void)in_sizes; (void)n_in; (void)out_size; (void)ws_size;
    const float* q = (const float*)d_in[0];
    const float* k = (const float*)d_in[1];
    const float* v = (const float*)d_in[2];
    float* out = (float*)d_out;

    prep<<<dim3(NH * NC), 256, 0, stream>>>(k, v, d_ws);
    scan<<<dim3(NH), 1024, 0, stream>>>(d_ws);
    attn<<<dim3(NH * NC), 256, 0, stream>>>(q, d_ws, out);
}